// Round 12
// baseline (417.603 us; speedup 1.0000x reference)
//
#include <hip/hip_runtime.h>
#include <hip/hip_bf16.h>
#include <hip/hip_fp16.h>
#include <cmath>

#define N_NODES 50000
#define N_EDGES 800000
#define HID 64
#define HEADS 4
#define CONVS 2
#define CLS 16
#define SLOPE 0.2f
#define SCAN_B 1024
#define LOG2E 1.4426950408889634f

typedef unsigned int  uint32;
typedef unsigned short ushort16;

__device__ __forceinline__ ushort16 f2bf(float x) {
    union { float f; uint32 u; } v; v.f = x;
    uint32 r = v.u + 0x7fffu + ((v.u >> 16) & 1u);   // RNE
    return (ushort16)(r >> 16);
}
__device__ __forceinline__ float bf_lo(uint32 w) { return __uint_as_float(w << 16); }
__device__ __forceinline__ float bf_hi(uint32 w) { return __uint_as_float(w & 0xffff0000u); }

// ------ fused: per-type projections (8 rows/wave, shfl-broadcast) + edge histogram ------

template <int K>
__device__ __forceinline__ void proj_body8(const float* __restrict__ feat,
                                           const float* __restrict__ W,
                                           const float* __restrict__ b,
                                           float* __restrict__ h,
                                           ushort16* __restrict__ hb,
                                           float* __restrict__ s_out,
                                           int rows, int base_row, int blk) {
    int lane = threadIdx.x & 63;
    int wid  = threadIdx.x >> 6;
    int r0 = (blk * 4 + wid) * 8;      // 8 rows per wave; rows % 8 == 0
    if (r0 >= rows) return;

    const float* a0 = feat + (size_t)r0 * K + lane;
    float bb = b[lane];
    float acc[8];
    #pragma unroll
    for (int i = 0; i < 8; i++) acc[i] = bb;

    constexpr int NCH = K / 64;
    float cur[8], nxt[8];
    #pragma unroll
    for (int i = 0; i < 8; i++) cur[i] = a0[(size_t)i * K];   // coalesced, per-row chunk 0

    #pragma unroll
    for (int c = 0; c < NCH; c++) {
        if (c + 1 < NCH) {
            #pragma unroll
            for (int i = 0; i < 8; i++) nxt[i] = a0[(size_t)i * K + (c + 1) * 64];
        }
        const float* wbase = W + (size_t)c * 64 * 64 + lane;
        #pragma unroll
        for (int t = 0; t < 64; t++) {
            float w = wbase[(size_t)t * 64];   // coalesced 256B, independent across t
            #pragma unroll
            for (int i = 0; i < 8; i++)
                acc[i] = fmaf(__shfl(cur[i], t), w, acc[i]);   // readlane broadcast
        }
        #pragma unroll
        for (int i = 0; i < 8; i++) cur[i] = nxt[i];
    }

    #pragma unroll
    for (int i = 0; i < 8; i++) {
        int gr = base_row + r0 + i;
        h[(size_t)gr * 64 + lane]  = acc[i];
        hb[(size_t)gr * 64 + lane] = f2bf(acc[i]);
    }
    #pragma unroll
    for (int i = 0; i < 8; i++) {
        float ssum = acc[i];
        #pragma unroll
        for (int off = 32; off; off >>= 1) ssum += __shfl_xor(ssum, off);
        if (lane == i) s_out[base_row + r0 + i] = ssum;   // lane i holds row i's sum
    }
}

#define PB0 625           // 20000 / 32
#define PB1 469           // ceil(15000 / 32)
#define PB2 469
#define NPROJ (PB0 + PB1 + PB2)
#define PBH ((N_EDGES + 1023) / 1024)   // 4 edges/thread

__global__ __launch_bounds__(256)
void fused_proj_hist_kernel(const float* __restrict__ feat0, const float* __restrict__ W1_0, const float* __restrict__ b1_0,
                            const float* __restrict__ feat1, const float* __restrict__ W1_1, const float* __restrict__ b1_1,
                            const float* __restrict__ feat2, const float* __restrict__ W1_2, const float* __restrict__ b1_2,
                            float* __restrict__ h, ushort16* __restrict__ hb, float* __restrict__ s_out,
                            const int* __restrict__ dst, int* __restrict__ deg) {
    int bid = blockIdx.x;
    if (bid < PB0) {
        proj_body8<256>(feat0, W1_0, b1_0, h, hb, s_out, 20000, 0, bid);
    } else if (bid < PB0 + PB1) {
        proj_body8<128>(feat1, W1_1, b1_1, h, hb, s_out, 15000, 20000, bid - PB0);
    } else if (bid < NPROJ) {
        proj_body8<64>(feat2, W1_2, b1_2, h, hb, s_out, 15000, 35000, bid - (PB0 + PB1));
    } else {
        int t4 = (bid - NPROJ) * 1024 + threadIdx.x * 4;
        if (t4 + 3 < N_EDGES) {
            int4 d4 = *reinterpret_cast<const int4*>(dst + t4);
            atomicAdd(&deg[d4.x], 1);
            atomicAdd(&deg[d4.y], 1);
            atomicAdd(&deg[d4.z], 1);
            atomicAdd(&deg[d4.w], 1);
        } else {
            for (int e = t4; e < N_EDGES; e++) atomicAdd(&deg[dst[e]], 1);
        }
    }
}

// ---------------- CSR scan ----------------

__global__ void scan1_kernel(const int* __restrict__ deg, int* __restrict__ row_ptr,
                             int* __restrict__ tops) {
    __shared__ int buf[SCAN_B];
    int i = blockIdx.x * SCAN_B + threadIdx.x;
    int v = (i < N_NODES) ? deg[i] : 0;
    buf[threadIdx.x] = v;
    __syncthreads();
    for (int off = 1; off < SCAN_B; off <<= 1) {
        int t = (threadIdx.x >= off) ? buf[threadIdx.x - off] : 0;
        __syncthreads();
        buf[threadIdx.x] += t;
        __syncthreads();
    }
    if (i < N_NODES) row_ptr[i + 1] = buf[threadIdx.x];
    if (threadIdx.x == SCAN_B - 1) tops[blockIdx.x] = buf[threadIdx.x];
}

__global__ void scan3_kernel(int* __restrict__ row_ptr, const int* __restrict__ tops) {
    __shared__ int pfx;
    if (threadIdx.x == 0) {
        int acc = 0;
        for (int b = 0; b < (int)blockIdx.x; b++) acc += tops[b];
        pfx = acc;
    }
    __syncthreads();
    int i = blockIdx.x * SCAN_B + threadIdx.x;
    if (i < N_NODES) row_ptr[i + 1] += pfx;
    if (i == 0 && blockIdx.x == 0) row_ptr[0] = 0;
}

__global__ void scatter_kernel(const int* __restrict__ src, const int* __restrict__ dst,
                               const int* __restrict__ row_ptr, int* __restrict__ cursor,
                               int* __restrict__ col) {
    int e = blockIdx.x * blockDim.x + threadIdx.x;
    if (e < 8) col[N_EDGES + e] = 0;   // pad (kept for safety)
    if (e < N_EDGES) {
        int d = dst[e];
        int pos = row_ptr[d] + atomicAdd(&cursor[d], 1);
        col[pos] = src[e];
    }
}

// ------- conv 0: lane-parallel edge metadata + shfl-broadcast loop, 4-deep x prefetch -----

__global__ __launch_bounds__(256)
void conv0_kernel(const ushort16* __restrict__ hb, const float* __restrict__ s_h,
                  const float* __restrict__ al, const float* __restrict__ ar,
                  const int* __restrict__ row_ptr, const int* __restrict__ col,
                  ushort16* __restrict__ x1p, float4* __restrict__ s1p) {
    int lane = threadIdx.x & 63;
    int wid  = threadIdx.x >> 6;
    int n = blockIdx.x * 4 + wid;
    if (n >= N_NODES) return;

    float sd = s_h[n];
    int base = row_ptr[n];
    int deg  = row_ptr[n + 1] - base;

    float alk[HEADS], ck[HEADS], alkB[HEADS], ckB[HEADS];
    float den[HEADS] = {0.f, 0.f, 0.f, 0.f}, num[HEADS] = {0.f, 0.f, 0.f, 0.f};
    #pragma unroll
    for (int hd = 0; hd < HEADS; hd++) {
        float a = al[(hd * CONVS + 0) * 64 + lane] * LOG2E;
        float c = ar[(hd * CONVS + 0) * 64 + lane] * LOG2E * sd;
        alk[hd] = a; ck[hd] = c; alkB[hd] = SLOPE * a; ckB[hd] = SLOPE * c;
    }

    const char* xb = (const char*)hb + (size_t)lane * 2;   // 2B/lane, row = 128B

#define XL0(KK) ((uint32)*reinterpret_cast<const ushort16*>(xb + (size_t)__shfl(cj, (KK) & 63) * 128))
#define C0C(J, XV)                                                                 \
    {                                                                              \
        float s_ = __shfl(sv, (J));                                                \
        float hf = __uint_as_float((XV) << 16);                                    \
        float w0 = exp2f(fmaxf(fmaf(alk[0], s_, ck[0]), fmaf(alkB[0], s_, ckB[0])));\
        float w1 = exp2f(fmaxf(fmaf(alk[1], s_, ck[1]), fmaf(alkB[1], s_, ckB[1])));\
        float w2 = exp2f(fmaxf(fmaf(alk[2], s_, ck[2]), fmaf(alkB[2], s_, ckB[2])));\
        float w3 = exp2f(fmaxf(fmaf(alk[3], s_, ck[3]), fmaf(alkB[3], s_, ckB[3])));\
        den[0] += w0; den[1] += w1; den[2] += w2; den[3] += w3;                    \
        num[0] = fmaf(hf, w0, num[0]); num[1] = fmaf(hf, w1, num[1]);              \
        num[2] = fmaf(hf, w2, num[2]); num[3] = fmaf(hf, w3, num[3]);              \
    }

    int done = 0;
    while (done < deg) {
        int CH = min(deg - done, 64);
        int cj = col[base + done + ((lane < CH) ? lane : 0)];  // coalesced; pad lanes = edge 0
        float sv = s_h[cj];                                    // per-lane gather, once
        uint32 xA = XL0(0), xB = XL0(1), xC = XL0(2), xD = XL0(3);
        int ch4 = CH & ~3;
        for (int j = 0; j < ch4; j += 4) {
            C0C(j + 0, xA); xA = XL0(j + 4);
            C0C(j + 1, xB); xB = XL0(j + 5);
            C0C(j + 2, xC); xC = XL0(j + 6);
            C0C(j + 3, xD); xD = XL0(j + 7);
        }
        int rem = CH - ch4;
        if (rem > 0) C0C(ch4 + 0, xA);
        if (rem > 1) C0C(ch4 + 1, xB);
        if (rem > 2) C0C(ch4 + 2, xC);
        done += CH;
    }
#undef XL0
#undef C0C

    float o[HEADS];
    #pragma unroll
    for (int hd = 0; hd < HEADS; hd++) o[hd] = num[hd] / den[hd];

    uint32 lo = ((uint32)f2bf(o[0])) | (((uint32)f2bf(o[1])) << 16);
    uint32 hi = ((uint32)f2bf(o[2])) | (((uint32)f2bf(o[3])) << 16);
    *reinterpret_cast<uint2*>(x1p + ((size_t)n * 64 + lane) * 4) = make_uint2(lo, hi);

    float s0 = o[0], s1v = o[1], s2 = o[2], s3 = o[3];
    #pragma unroll
    for (int off = 32; off; off >>= 1) {
        s0 += __shfl_xor(s0, off); s1v += __shfl_xor(s1v, off);
        s2 += __shfl_xor(s2, off); s3  += __shfl_xor(s3, off);
    }
    if (lane == 0) s1p[n] = make_float4(s0, s1v, s2, s3);
}

// ------- conv 1: lane-parallel edge metadata + shfl-broadcast loop, 4-deep x prefetch ----

__global__ __launch_bounds__(256)
void conv1_kernel(const float* __restrict__ h, const ushort16* __restrict__ x1p,
                  const float4* __restrict__ s1p,
                  const float* __restrict__ al, const float* __restrict__ ar,
                  const int* __restrict__ row_ptr, const int* __restrict__ col,
                  uint2* __restrict__ zh /* [N][64 lanes][4 heads] fp16 */) {
    int lane = threadIdx.x & 63;
    int wid  = threadIdx.x >> 6;
    int n = blockIdx.x * 4 + wid;
    if (n >= N_NODES) return;

    int base = row_ptr[n];
    int deg  = row_ptr[n + 1] - base;

    float4 sdn = s1p[n];
    float sdv[HEADS] = {sdn.x, sdn.y, sdn.z, sdn.w};
    float alk[HEADS], ck[HEADS], alkB[HEADS], ckB[HEADS];
    float den[HEADS] = {0.f, 0.f, 0.f, 0.f}, num[HEADS] = {0.f, 0.f, 0.f, 0.f};
    #pragma unroll
    for (int hd = 0; hd < HEADS; hd++) {
        float a = al[(hd * CONVS + 1) * 64 + lane] * LOG2E;
        float c = ar[(hd * CONVS + 1) * 64 + lane] * LOG2E * sdv[hd];
        alk[hd] = a; ck[hd] = c; alkB[hd] = SLOPE * a; ckB[hd] = SLOPE * c;
    }

    const char* xb = (const char*)x1p + (size_t)lane * 8;   // 8B/lane, row = 512B

#define XL1(KK) (*reinterpret_cast<const uint2*>(xb + (size_t)__shfl(cj, (KK) & 63) * 512))
#define C1C(J, XV)                                                                 \
    {                                                                              \
        float s0_ = __shfl(s4.x, (J)), s1_ = __shfl(s4.y, (J));                    \
        float s2_ = __shfl(s4.z, (J)), s3_ = __shfl(s4.w, (J));                    \
        float xf0 = bf_lo((XV).x), xf1 = bf_hi((XV).x);                            \
        float xf2 = bf_lo((XV).y), xf3 = bf_hi((XV).y);                            \
        float w0 = exp2f(fmaxf(fmaf(alk[0], s0_, ck[0]), fmaf(alkB[0], s0_, ckB[0])));\
        float w1 = exp2f(fmaxf(fmaf(alk[1], s1_, ck[1]), fmaf(alkB[1], s1_, ckB[1])));\
        float w2 = exp2f(fmaxf(fmaf(alk[2], s2_, ck[2]), fmaf(alkB[2], s2_, ckB[2])));\
        float w3 = exp2f(fmaxf(fmaf(alk[3], s3_, ck[3]), fmaf(alkB[3], s3_, ckB[3])));\
        den[0] += w0; den[1] += w1; den[2] += w2; den[3] += w3;                    \
        num[0] = fmaf(xf0, w0, num[0]); num[1] = fmaf(xf1, w1, num[1]);            \
        num[2] = fmaf(xf2, w2, num[2]); num[3] = fmaf(xf3, w3, num[3]);            \
    }

    int done = 0;
    while (done < deg) {
        int CH = min(deg - done, 64);
        int cj = col[base + done + ((lane < CH) ? lane : 0)];  // coalesced; pad lanes = edge 0
        float4 s4 = s1p[cj];                                   // per-lane gather, once
        uint2 xA = XL1(0), xB = XL1(1), xC = XL1(2), xD = XL1(3);
        int ch4 = CH & ~3;
        for (int j = 0; j < ch4; j += 4) {
            C1C(j + 0, xA); xA = XL1(j + 4);
            C1C(j + 1, xB); xB = XL1(j + 5);
            C1C(j + 2, xC); xC = XL1(j + 6);
            C1C(j + 3, xD); xD = XL1(j + 7);
        }
        int rem = CH - ch4;
        if (rem > 0) C1C(ch4 + 0, xA);
        if (rem > 1) C1C(ch4 + 1, xB);
        if (rem > 2) C1C(ch4 + 2, xC);
        done += CH;
    }
#undef XL1
#undef C1C

    float hres = h[(size_t)n * 64 + lane];
    float z0 = fmaxf(hres + num[0] / den[0], 0.f);
    float z1 = fmaxf(hres + num[1] / den[1], 0.f);
    float z2 = fmaxf(hres + num[2] / den[2], 0.f);
    float z3 = fmaxf(hres + num[3] / den[3], 0.f);

    __half2 p01 = __floats2half2_rn(z0, z1);
    __half2 p23 = __floats2half2_rn(z2, z3);
    uint2 pk;
    pk.x = *reinterpret_cast<uint32*>(&p01);
    pk.y = *reinterpret_cast<uint32*>(&p23);
    zh[(size_t)n * 64 + lane] = pk;   // coalesced 512B per wave
}

// ------- encoded = z @ W2 + b2, then logits = relu(enc) @ W3 + b3 (fused) -------

__global__ __launch_bounds__(256)
void zgemm_kernel(const uint2* __restrict__ zh, const float* __restrict__ W2,
                  const float* __restrict__ b2, const float* __restrict__ W3,
                  const float* __restrict__ b3,
                  float* __restrict__ out_encoded, float* __restrict__ out_logits) {
    int lane = threadIdx.x & 63;
    int wid  = threadIdx.x >> 6;
    int r0 = (blockIdx.x * 4 + wid) * 4;      // 4 rows per wave
    if (r0 >= N_NODES) return;

    float bb = b2[lane];
    float a0 = bb, a1 = bb, a2 = bb, a3 = bb;
    const uint2* z0 = zh + (size_t)r0 * 64;

    for (int q = 0; q < 64; q += 2) {
        const float* wp = W2 + q * 64 + lane;
        float w0 = wp[0];            // (hd0, q)
        float w1 = wp[4096];         // (hd1, q)
        float w2 = wp[8192];         // (hd2, q)
        float w3 = wp[12288];        // (hd3, q)
        float w4 = wp[64];           // (hd0, q+1)
        float w5 = wp[4160];         // (hd1, q+1)
        float w6 = wp[8256];         // (hd2, q+1)
        float w7 = wp[12352];        // (hd3, q+1)

        #pragma unroll
        for (int rr = 0; rr < 4; rr++) {
            uint4 zz = *reinterpret_cast<const uint4*>(z0 + rr * 64 + q);
            float2 fA = __half22float2(*reinterpret_cast<const __half2*>(&zz.x));
            float2 fB = __half22float2(*reinterpret_cast<const __half2*>(&zz.y));
            float2 fC = __half22float2(*reinterpret_cast<const __half2*>(&zz.z));
            float2 fD = __half22float2(*reinterpret_cast<const __half2*>(&zz.w));
            float acc = (rr == 0) ? a0 : (rr == 1) ? a1 : (rr == 2) ? a2 : a3;
            acc = fmaf(fA.x, w0, acc);
            acc = fmaf(fA.y, w1, acc);
            acc = fmaf(fB.x, w2, acc);
            acc = fmaf(fB.y, w3, acc);
            acc = fmaf(fC.x, w4, acc);
            acc = fmaf(fC.y, w5, acc);
            acc = fmaf(fD.x, w6, acc);
            acc = fmaf(fD.y, w7, acc);
            if (rr == 0) a0 = acc; else if (rr == 1) a1 = acc; else if (rr == 2) a2 = acc; else a3 = acc;
        }
    }
    out_encoded[(size_t)(r0 + 0) * 64 + lane] = a0;
    out_encoded[(size_t)(r0 + 1) * 64 + lane] = a1;
    out_encoded[(size_t)(r0 + 2) * 64 + lane] = a2;
    out_encoded[(size_t)(r0 + 3) * 64 + lane] = a3;

    // fused logits: lane holds enc col; per row 16 shuffles + 2-step reduce
    int c16 = lane & 15;
    int k0  = (lane >> 4) * 16;
    float accs[4] = {a0, a1, a2, a3};
    #pragma unroll
    for (int rr = 0; rr < 4; rr++) {
        float er = fmaxf(accs[rr], 0.f);
        float part = 0.f;
        #pragma unroll
        for (int j = 0; j < 16; j++) {
            float ev = __shfl(er, k0 + j);
            part = fmaf(ev, W3[(k0 + j) * CLS + c16], part);
        }
        part += __shfl_xor(part, 16);
        part += __shfl_xor(part, 32);
        if (lane < CLS) out_logits[(size_t)(r0 + rr) * CLS + lane] = part + b3[lane];
    }
}

// ---------------- launch ----------------

extern "C" void kernel_launch(void* const* d_in, const int* in_sizes, int n_in,
                              void* d_out, int out_size, void* d_ws, size_t ws_size,
                              hipStream_t stream) {
    const float* feat0 = (const float*)d_in[0];
    const float* feat1 = (const float*)d_in[1];
    const float* feat2 = (const float*)d_in[2];
    const int*   src   = (const int*)d_in[3];
    const int*   dst   = (const int*)d_in[4];
    const float* W1_0  = (const float*)d_in[5];
    const float* b1_0  = (const float*)d_in[6];
    const float* W1_1  = (const float*)d_in[7];
    const float* b1_1  = (const float*)d_in[8];
    const float* W1_2  = (const float*)d_in[9];
    const float* b1_2  = (const float*)d_in[10];
    const float* al    = (const float*)d_in[11];
    const float* ar    = (const float*)d_in[12];
    const float* W2    = (const float*)d_in[13];
    const float* b2    = (const float*)d_in[14];
    const float* W3    = (const float*)d_in[15];
    const float* b3    = (const float*)d_in[16];

    float* out_logits  = (float*)d_out;
    float* out_encoded = (float*)d_out + (size_t)N_NODES * CLS;

    char* ws = (char*)d_ws;
    size_t off = 0;
    auto alloc = [&](size_t bytes) {
        void* p = ws + off;
        off = (off + bytes + 255) & ~(size_t)255;
        return p;
    };
    int*      row_ptr = (int*)alloc((N_NODES + 1) * sizeof(int));
    int*      degcur  = (int*)alloc(2 * N_NODES * sizeof(int));  // deg | cursor
    int*      tops    = (int*)alloc(64 * sizeof(int));
    int*      col     = (int*)alloc(((size_t)N_EDGES + 8) * sizeof(int));
    float*    h       = (float*)alloc((size_t)N_NODES * 64 * sizeof(float));
    ushort16* hb      = (ushort16*)alloc((size_t)N_NODES * 64 * sizeof(ushort16));
    float*    s_h     = (float*)alloc(N_NODES * sizeof(float));
    ushort16* x1p     = (ushort16*)alloc((size_t)N_NODES * 64 * 4 * sizeof(ushort16));
    float4*   s1p     = (float4*)alloc(N_NODES * sizeof(float4));
    uint2*    zh      = (uint2*)alloc((size_t)N_NODES * 64 * sizeof(uint2));
    int* deg    = degcur;
    int* cursor = degcur + N_NODES;
    (void)ws_size; (void)in_sizes; (void)n_in; (void)out_size;

    // zero deg + cursor in one shot
    (void)hipMemsetAsync(degcur, 0, 2 * N_NODES * sizeof(int), stream);

    // fused projections (8 rows/wave, shfl-broadcast) + histogram (4 edges/thread)
    fused_proj_hist_kernel<<<NPROJ + PBH, 256, 0, stream>>>(
        feat0, W1_0, b1_0, feat1, W1_1, b1_1, feat2, W1_2, b1_2,
        h, hb, s_h, dst, deg);

    int nb = (N_NODES + SCAN_B - 1) / SCAN_B;
    scan1_kernel<<<nb, SCAN_B, 0, stream>>>(deg, row_ptr, tops);
    scan3_kernel<<<nb, SCAN_B, 0, stream>>>(row_ptr, tops);
    scatter_kernel<<<(N_EDGES + 255) / 256, 256, 0, stream>>>(src, dst, row_ptr, cursor, col);

    // convs (1 wave per node)
    conv0_kernel<<<(N_NODES + 3) / 4, 256, 0, stream>>>(hb, s_h, al, ar, row_ptr, col, x1p, s1p);
    conv1_kernel<<<(N_NODES + 3) / 4, 256, 0, stream>>>(h, x1p, s1p, al, ar, row_ptr, col, zh);

    // fused epilogue GEMM (encoded + logits)
    zgemm_kernel<<<(N_NODES / 16), 256, 0, stream>>>(zh, W2, b2, W3, b3, out_encoded, out_logits);
}

// Round 13
// 353.805 us; speedup vs baseline: 1.1803x; 1.1803x over previous
//
#include <hip/hip_runtime.h>
#include <hip/hip_bf16.h>
#include <hip/hip_fp16.h>
#include <cmath>

#define N_NODES 50000
#define N_EDGES 800000
#define HID 64
#define HEADS 4
#define CONVS 2
#define CLS 16
#define SLOPE 0.2f
#define SCAN_B 1024
#define LOG2E 1.4426950408889634f

typedef unsigned int  uint32;
typedef unsigned short ushort16;

__device__ __forceinline__ ushort16 f2bf(float x) {
    union { float f; uint32 u; } v; v.f = x;
    uint32 r = v.u + 0x7fffu + ((v.u >> 16) & 1u);   // RNE
    return (ushort16)(r >> 16);
}
__device__ __forceinline__ float bf_lo(uint32 w) { return __uint_as_float(w << 16); }
__device__ __forceinline__ float bf_hi(uint32 w) { return __uint_as_float(w & 0xffff0000u); }

// ------ fused: per-type projections (LDS-staged feat tile) + edge histogram ------

template <int K>
__device__ __forceinline__ void proj_lds(const float* __restrict__ feat,
                                         const float* __restrict__ W,
                                         const float* __restrict__ b,
                                         float* __restrict__ h,
                                         ushort16* __restrict__ hb,
                                         float* __restrict__ s_out,
                                         int rows, int base_row, int blk,
                                         float* __restrict__ lds) {
    int tid  = threadIdx.x;
    int lane = tid & 63;
    int wid  = tid >> 6;
    int tile0 = blk * 32;                       // 32 rows per block
    int avail = rows - tile0; if (avail > 32) avail = 32;   // rows%8==0 -> avail%8==0

    // stage avail×K floats, coalesced float4 loads
    const float4* g = reinterpret_cast<const float4*>(feat + (size_t)tile0 * K);
    float4* l4 = reinterpret_cast<float4*>(lds);
    int nv = avail * K / 4;
    for (int i = tid; i < nv; i += 256) l4[i] = g[i];
    __syncthreads();

    int r0 = wid * 8;                           // local row base for this wave
    if (r0 >= avail) return;

    float bb = b[lane];
    float acc[8];
    #pragma unroll
    for (int i = 0; i < 8; i++) acc[i] = bb;

    for (int kk = 0; kk < K; kk += 4) {
        float w0 = W[(kk + 0) * 64 + lane];
        float w1 = W[(kk + 1) * 64 + lane];
        float w2 = W[(kk + 2) * 64 + lane];
        float w3 = W[(kk + 3) * 64 + lane];
        #pragma unroll
        for (int i = 0; i < 8; i++) {
            float4 a4 = *reinterpret_cast<const float4*>(lds + (size_t)(r0 + i) * K + kk); // uniform addr -> LDS broadcast
            acc[i] = fmaf(a4.x, w0, acc[i]);
            acc[i] = fmaf(a4.y, w1, acc[i]);
            acc[i] = fmaf(a4.z, w2, acc[i]);
            acc[i] = fmaf(a4.w, w3, acc[i]);
        }
    }

    #pragma unroll
    for (int i = 0; i < 8; i++) {
        int gr = base_row + tile0 + r0 + i;
        h[(size_t)gr * 64 + lane]  = acc[i];
        hb[(size_t)gr * 64 + lane] = f2bf(acc[i]);
    }
    #pragma unroll
    for (int i = 0; i < 8; i++) {
        float ssum = acc[i];
        #pragma unroll
        for (int off = 32; off; off >>= 1) ssum += __shfl_xor(ssum, off);
        if (lane == i) s_out[base_row + tile0 + r0 + i] = ssum;
    }
}

#define PB0 625           // 20000 / 32
#define PB1 469           // ceil(15000 / 32)
#define PB2 469
#define NPROJ (PB0 + PB1 + PB2)
#define PBH ((N_EDGES + 1023) / 1024)   // 4 edges/thread

__global__ __launch_bounds__(256)
void fused_proj_hist_kernel(const float* __restrict__ feat0, const float* __restrict__ W1_0, const float* __restrict__ b1_0,
                            const float* __restrict__ feat1, const float* __restrict__ W1_1, const float* __restrict__ b1_1,
                            const float* __restrict__ feat2, const float* __restrict__ W1_2, const float* __restrict__ b1_2,
                            float* __restrict__ h, ushort16* __restrict__ hb, float* __restrict__ s_out,
                            const int* __restrict__ dst, int* __restrict__ deg) {
    __shared__ float lds[32 * 256];   // 32 KB
    int bid = blockIdx.x;
    if (bid < PB0) {
        proj_lds<256>(feat0, W1_0, b1_0, h, hb, s_out, 20000, 0, bid, lds);
    } else if (bid < PB0 + PB1) {
        proj_lds<128>(feat1, W1_1, b1_1, h, hb, s_out, 15000, 20000, bid - PB0, lds);
    } else if (bid < NPROJ) {
        proj_lds<64>(feat2, W1_2, b1_2, h, hb, s_out, 15000, 35000, bid - (PB0 + PB1), lds);
    } else {
        int t4 = (bid - NPROJ) * 1024 + threadIdx.x * 4;
        if (t4 + 3 < N_EDGES) {
            int4 d4 = *reinterpret_cast<const int4*>(dst + t4);
            atomicAdd(&deg[d4.x], 1);
            atomicAdd(&deg[d4.y], 1);
            atomicAdd(&deg[d4.z], 1);
            atomicAdd(&deg[d4.w], 1);
        } else {
            for (int e = t4; e < N_EDGES; e++) atomicAdd(&deg[dst[e]], 1);
        }
    }
}

// ---------------- CSR scan ----------------

__global__ void scan1_kernel(const int* __restrict__ deg, int* __restrict__ row_ptr,
                             int* __restrict__ tops) {
    __shared__ int buf[SCAN_B];
    int i = blockIdx.x * SCAN_B + threadIdx.x;
    int v = (i < N_NODES) ? deg[i] : 0;
    buf[threadIdx.x] = v;
    __syncthreads();
    for (int off = 1; off < SCAN_B; off <<= 1) {
        int t = (threadIdx.x >= off) ? buf[threadIdx.x - off] : 0;
        __syncthreads();
        buf[threadIdx.x] += t;
        __syncthreads();
    }
    if (i < N_NODES) row_ptr[i + 1] = buf[threadIdx.x];
    if (threadIdx.x == SCAN_B - 1) tops[blockIdx.x] = buf[threadIdx.x];
}

__global__ void scan3_kernel(int* __restrict__ row_ptr, const int* __restrict__ tops) {
    __shared__ int pfx;
    if (threadIdx.x == 0) {
        int acc = 0;
        for (int b = 0; b < (int)blockIdx.x; b++) acc += tops[b];
        pfx = acc;
    }
    __syncthreads();
    int i = blockIdx.x * SCAN_B + threadIdx.x;
    if (i < N_NODES) row_ptr[i + 1] += pfx;
    if (i == 0 && blockIdx.x == 0) row_ptr[0] = 0;
}

__global__ void scatter_kernel(const int* __restrict__ src, const int* __restrict__ dst,
                               const int* __restrict__ row_ptr, int* __restrict__ cursor,
                               int* __restrict__ col) {
    int e = blockIdx.x * blockDim.x + threadIdx.x;
    if (e < 8) col[N_EDGES + e] = 0;   // pad (kept for safety)
    if (e < N_EDGES) {
        int d = dst[e];
        int pos = row_ptr[d] + atomicAdd(&cursor[d], 1);
        col[pos] = src[e];
    }
}

// ------- conv 0: lane-parallel edge metadata + shfl-broadcast loop, 4-deep x prefetch -----

__global__ __launch_bounds__(256)
void conv0_kernel(const ushort16* __restrict__ hb, const float* __restrict__ s_h,
                  const float* __restrict__ al, const float* __restrict__ ar,
                  const int* __restrict__ row_ptr, const int* __restrict__ col,
                  ushort16* __restrict__ x1p, float4* __restrict__ s1p) {
    int lane = threadIdx.x & 63;
    int wid  = threadIdx.x >> 6;
    int n = blockIdx.x * 4 + wid;
    if (n >= N_NODES) return;

    float sd = s_h[n];
    int base = row_ptr[n];
    int deg  = row_ptr[n + 1] - base;

    float alk[HEADS], ck[HEADS], alkB[HEADS], ckB[HEADS];
    float den[HEADS] = {0.f, 0.f, 0.f, 0.f}, num[HEADS] = {0.f, 0.f, 0.f, 0.f};
    #pragma unroll
    for (int hd = 0; hd < HEADS; hd++) {
        float a = al[(hd * CONVS + 0) * 64 + lane] * LOG2E;
        float c = ar[(hd * CONVS + 0) * 64 + lane] * LOG2E * sd;
        alk[hd] = a; ck[hd] = c; alkB[hd] = SLOPE * a; ckB[hd] = SLOPE * c;
    }

    const char* xb = (const char*)hb + (size_t)lane * 2;   // 2B/lane, row = 128B

#define XL0(KK) ((uint32)*reinterpret_cast<const ushort16*>(xb + (size_t)__shfl(cj, (KK) & 63) * 128))
#define C0C(J, XV)                                                                 \
    {                                                                              \
        float s_ = __shfl(sv, (J));                                                \
        float hf = __uint_as_float((XV) << 16);                                    \
        float w0 = exp2f(fmaxf(fmaf(alk[0], s_, ck[0]), fmaf(alkB[0], s_, ckB[0])));\
        float w1 = exp2f(fmaxf(fmaf(alk[1], s_, ck[1]), fmaf(alkB[1], s_, ckB[1])));\
        float w2 = exp2f(fmaxf(fmaf(alk[2], s_, ck[2]), fmaf(alkB[2], s_, ckB[2])));\
        float w3 = exp2f(fmaxf(fmaf(alk[3], s_, ck[3]), fmaf(alkB[3], s_, ckB[3])));\
        den[0] += w0; den[1] += w1; den[2] += w2; den[3] += w3;                    \
        num[0] = fmaf(hf, w0, num[0]); num[1] = fmaf(hf, w1, num[1]);              \
        num[2] = fmaf(hf, w2, num[2]); num[3] = fmaf(hf, w3, num[3]);              \
    }

    int done = 0;
    while (done < deg) {
        int CH = min(deg - done, 64);
        int cj = col[base + done + ((lane < CH) ? lane : 0)];  // coalesced; pad lanes = edge 0
        float sv = s_h[cj];                                    // per-lane gather, once
        uint32 xA = XL0(0), xB = XL0(1), xC = XL0(2), xD = XL0(3);
        int ch4 = CH & ~3;
        for (int j = 0; j < ch4; j += 4) {
            C0C(j + 0, xA); xA = XL0(j + 4);
            C0C(j + 1, xB); xB = XL0(j + 5);
            C0C(j + 2, xC); xC = XL0(j + 6);
            C0C(j + 3, xD); xD = XL0(j + 7);
        }
        int rem = CH - ch4;
        if (rem > 0) C0C(ch4 + 0, xA);
        if (rem > 1) C0C(ch4 + 1, xB);
        if (rem > 2) C0C(ch4 + 2, xC);
        done += CH;
    }
#undef XL0
#undef C0C

    float o[HEADS];
    #pragma unroll
    for (int hd = 0; hd < HEADS; hd++) o[hd] = num[hd] / den[hd];

    uint32 lo = ((uint32)f2bf(o[0])) | (((uint32)f2bf(o[1])) << 16);
    uint32 hi = ((uint32)f2bf(o[2])) | (((uint32)f2bf(o[3])) << 16);
    *reinterpret_cast<uint2*>(x1p + ((size_t)n * 64 + lane) * 4) = make_uint2(lo, hi);

    float s0 = o[0], s1v = o[1], s2 = o[2], s3 = o[3];
    #pragma unroll
    for (int off = 32; off; off >>= 1) {
        s0 += __shfl_xor(s0, off); s1v += __shfl_xor(s1v, off);
        s2 += __shfl_xor(s2, off); s3  += __shfl_xor(s3, off);
    }
    if (lane == 0) s1p[n] = make_float4(s0, s1v, s2, s3);
}

// ------- conv 1: lane-parallel edge metadata + shfl-broadcast loop, 4-deep x prefetch ----

__global__ __launch_bounds__(256)
void conv1_kernel(const float* __restrict__ h, const ushort16* __restrict__ x1p,
                  const float4* __restrict__ s1p,
                  const float* __restrict__ al, const float* __restrict__ ar,
                  const int* __restrict__ row_ptr, const int* __restrict__ col,
                  uint2* __restrict__ zh /* [N][64 lanes][4 heads] fp16 */) {
    int lane = threadIdx.x & 63;
    int wid  = threadIdx.x >> 6;
    int n = blockIdx.x * 4 + wid;
    if (n >= N_NODES) return;

    int base = row_ptr[n];
    int deg  = row_ptr[n + 1] - base;

    float4 sdn = s1p[n];
    float sdv[HEADS] = {sdn.x, sdn.y, sdn.z, sdn.w};
    float alk[HEADS], ck[HEADS], alkB[HEADS], ckB[HEADS];
    float den[HEADS] = {0.f, 0.f, 0.f, 0.f}, num[HEADS] = {0.f, 0.f, 0.f, 0.f};
    #pragma unroll
    for (int hd = 0; hd < HEADS; hd++) {
        float a = al[(hd * CONVS + 1) * 64 + lane] * LOG2E;
        float c = ar[(hd * CONVS + 1) * 64 + lane] * LOG2E * sdv[hd];
        alk[hd] = a; ck[hd] = c; alkB[hd] = SLOPE * a; ckB[hd] = SLOPE * c;
    }

    const char* xb = (const char*)x1p + (size_t)lane * 8;   // 8B/lane, row = 512B

#define XL1(KK) (*reinterpret_cast<const uint2*>(xb + (size_t)__shfl(cj, (KK) & 63) * 512))
#define C1C(J, XV)                                                                 \
    {                                                                              \
        float s0_ = __shfl(s4.x, (J)), s1_ = __shfl(s4.y, (J));                    \
        float s2_ = __shfl(s4.z, (J)), s3_ = __shfl(s4.w, (J));                    \
        float xf0 = bf_lo((XV).x), xf1 = bf_hi((XV).x);                            \
        float xf2 = bf_lo((XV).y), xf3 = bf_hi((XV).y);                            \
        float w0 = exp2f(fmaxf(fmaf(alk[0], s0_, ck[0]), fmaf(alkB[0], s0_, ckB[0])));\
        float w1 = exp2f(fmaxf(fmaf(alk[1], s1_, ck[1]), fmaf(alkB[1], s1_, ckB[1])));\
        float w2 = exp2f(fmaxf(fmaf(alk[2], s2_, ck[2]), fmaf(alkB[2], s2_, ckB[2])));\
        float w3 = exp2f(fmaxf(fmaf(alk[3], s3_, ck[3]), fmaf(alkB[3], s3_, ckB[3])));\
        den[0] += w0; den[1] += w1; den[2] += w2; den[3] += w3;                    \
        num[0] = fmaf(xf0, w0, num[0]); num[1] = fmaf(xf1, w1, num[1]);            \
        num[2] = fmaf(xf2, w2, num[2]); num[3] = fmaf(xf3, w3, num[3]);            \
    }

    int done = 0;
    while (done < deg) {
        int CH = min(deg - done, 64);
        int cj = col[base + done + ((lane < CH) ? lane : 0)];  // coalesced; pad lanes = edge 0
        float4 s4 = s1p[cj];                                   // per-lane gather, once
        uint2 xA = XL1(0), xB = XL1(1), xC = XL1(2), xD = XL1(3);
        int ch4 = CH & ~3;
        for (int j = 0; j < ch4; j += 4) {
            C1C(j + 0, xA); xA = XL1(j + 4);
            C1C(j + 1, xB); xB = XL1(j + 5);
            C1C(j + 2, xC); xC = XL1(j + 6);
            C1C(j + 3, xD); xD = XL1(j + 7);
        }
        int rem = CH - ch4;
        if (rem > 0) C1C(ch4 + 0, xA);
        if (rem > 1) C1C(ch4 + 1, xB);
        if (rem > 2) C1C(ch4 + 2, xC);
        done += CH;
    }
#undef XL1
#undef C1C

    float hres = h[(size_t)n * 64 + lane];
    float z0 = fmaxf(hres + num[0] / den[0], 0.f);
    float z1 = fmaxf(hres + num[1] / den[1], 0.f);
    float z2 = fmaxf(hres + num[2] / den[2], 0.f);
    float z3 = fmaxf(hres + num[3] / den[3], 0.f);

    __half2 p01 = __floats2half2_rn(z0, z1);
    __half2 p23 = __floats2half2_rn(z2, z3);
    uint2 pk;
    pk.x = *reinterpret_cast<uint32*>(&p01);
    pk.y = *reinterpret_cast<uint32*>(&p23);
    zh[(size_t)n * 64 + lane] = pk;   // coalesced 512B per wave
}

// ------- encoded = z @ W2 + b2, then logits = relu(enc) @ W3 + b3 (fused) -------

__global__ __launch_bounds__(256)
void zgemm_kernel(const uint2* __restrict__ zh, const float* __restrict__ W2,
                  const float* __restrict__ b2, const float* __restrict__ W3,
                  const float* __restrict__ b3,
                  float* __restrict__ out_encoded, float* __restrict__ out_logits) {
    int lane = threadIdx.x & 63;
    int wid  = threadIdx.x >> 6;
    int r0 = (blockIdx.x * 4 + wid) * 4;      // 4 rows per wave
    if (r0 >= N_NODES) return;

    float bb = b2[lane];
    float a0 = bb, a1 = bb, a2 = bb, a3 = bb;
    const uint2* z0 = zh + (size_t)r0 * 64;

    for (int q = 0; q < 64; q += 2) {
        const float* wp = W2 + q * 64 + lane;
        float w0 = wp[0];            // (hd0, q)
        float w1 = wp[4096];         // (hd1, q)
        float w2 = wp[8192];         // (hd2, q)
        float w3 = wp[12288];        // (hd3, q)
        float w4 = wp[64];           // (hd0, q+1)
        float w5 = wp[4160];         // (hd1, q+1)
        float w6 = wp[8256];         // (hd2, q+1)
        float w7 = wp[12352];        // (hd3, q+1)

        #pragma unroll
        for (int rr = 0; rr < 4; rr++) {
            uint4 zz = *reinterpret_cast<const uint4*>(z0 + rr * 64 + q);
            float2 fA = __half22float2(*reinterpret_cast<const __half2*>(&zz.x));
            float2 fB = __half22float2(*reinterpret_cast<const __half2*>(&zz.y));
            float2 fC = __half22float2(*reinterpret_cast<const __half2*>(&zz.z));
            float2 fD = __half22float2(*reinterpret_cast<const __half2*>(&zz.w));
            float acc = (rr == 0) ? a0 : (rr == 1) ? a1 : (rr == 2) ? a2 : a3;
            acc = fmaf(fA.x, w0, acc);
            acc = fmaf(fA.y, w1, acc);
            acc = fmaf(fB.x, w2, acc);
            acc = fmaf(fB.y, w3, acc);
            acc = fmaf(fC.x, w4, acc);
            acc = fmaf(fC.y, w5, acc);
            acc = fmaf(fD.x, w6, acc);
            acc = fmaf(fD.y, w7, acc);
            if (rr == 0) a0 = acc; else if (rr == 1) a1 = acc; else if (rr == 2) a2 = acc; else a3 = acc;
        }
    }
    out_encoded[(size_t)(r0 + 0) * 64 + lane] = a0;
    out_encoded[(size_t)(r0 + 1) * 64 + lane] = a1;
    out_encoded[(size_t)(r0 + 2) * 64 + lane] = a2;
    out_encoded[(size_t)(r0 + 3) * 64 + lane] = a3;

    // fused logits: lane holds enc col; per row 16 shuffles + 2-step reduce
    int c16 = lane & 15;
    int k0  = (lane >> 4) * 16;
    float accs[4] = {a0, a1, a2, a3};
    #pragma unroll
    for (int rr = 0; rr < 4; rr++) {
        float er = fmaxf(accs[rr], 0.f);
        float part = 0.f;
        #pragma unroll
        for (int j = 0; j < 16; j++) {
            float ev = __shfl(er, k0 + j);
            part = fmaf(ev, W3[(k0 + j) * CLS + c16], part);
        }
        part += __shfl_xor(part, 16);
        part += __shfl_xor(part, 32);
        if (lane < CLS) out_logits[(size_t)(r0 + rr) * CLS + lane] = part + b3[lane];
    }
}

// ---------------- launch ----------------

extern "C" void kernel_launch(void* const* d_in, const int* in_sizes, int n_in,
                              void* d_out, int out_size, void* d_ws, size_t ws_size,
                              hipStream_t stream) {
    const float* feat0 = (const float*)d_in[0];
    const float* feat1 = (const float*)d_in[1];
    const float* feat2 = (const float*)d_in[2];
    const int*   src   = (const int*)d_in[3];
    const int*   dst   = (const int*)d_in[4];
    const float* W1_0  = (const float*)d_in[5];
    const float* b1_0  = (const float*)d_in[6];
    const float* W1_1  = (const float*)d_in[7];
    const float* b1_1  = (const float*)d_in[8];
    const float* W1_2  = (const float*)d_in[9];
    const float* b1_2  = (const float*)d_in[10];
    const float* al    = (const float*)d_in[11];
    const float* ar    = (const float*)d_in[12];
    const float* W2    = (const float*)d_in[13];
    const float* b2    = (const float*)d_in[14];
    const float* W3    = (const float*)d_in[15];
    const float* b3    = (const float*)d_in[16];

    float* out_logits  = (float*)d_out;
    float* out_encoded = (float*)d_out + (size_t)N_NODES * CLS;

    char* ws = (char*)d_ws;
    size_t off = 0;
    auto alloc = [&](size_t bytes) {
        void* p = ws + off;
        off = (off + bytes + 255) & ~(size_t)255;
        return p;
    };
    int*      row_ptr = (int*)alloc((N_NODES + 1) * sizeof(int));
    int*      degcur  = (int*)alloc(2 * N_NODES * sizeof(int));  // deg | cursor
    int*      tops    = (int*)alloc(64 * sizeof(int));
    int*      col     = (int*)alloc(((size_t)N_EDGES + 8) * sizeof(int));
    float*    h       = (float*)alloc((size_t)N_NODES * 64 * sizeof(float));
    ushort16* hb      = (ushort16*)alloc((size_t)N_NODES * 64 * sizeof(ushort16));
    float*    s_h     = (float*)alloc(N_NODES * sizeof(float));
    ushort16* x1p     = (ushort16*)alloc((size_t)N_NODES * 64 * 4 * sizeof(ushort16));
    float4*   s1p     = (float4*)alloc(N_NODES * sizeof(float4));
    uint2*    zh      = (uint2*)alloc((size_t)N_NODES * 64 * sizeof(uint2));
    int* deg    = degcur;
    int* cursor = degcur + N_NODES;
    (void)ws_size; (void)in_sizes; (void)n_in; (void)out_size;

    // zero deg + cursor in one shot
    (void)hipMemsetAsync(degcur, 0, 2 * N_NODES * sizeof(int), stream);

    // fused projections (LDS-staged, 8 rows/wave) + histogram (4 edges/thread)
    fused_proj_hist_kernel<<<NPROJ + PBH, 256, 0, stream>>>(
        feat0, W1_0, b1_0, feat1, W1_1, b1_1, feat2, W1_2, b1_2,
        h, hb, s_h, dst, deg);

    int nb = (N_NODES + SCAN_B - 1) / SCAN_B;
    scan1_kernel<<<nb, SCAN_B, 0, stream>>>(deg, row_ptr, tops);
    scan3_kernel<<<nb, SCAN_B, 0, stream>>>(row_ptr, tops);
    scatter_kernel<<<(N_EDGES + 255) / 256, 256, 0, stream>>>(src, dst, row_ptr, cursor, col);

    // convs (1 wave per node)
    conv0_kernel<<<(N_NODES + 3) / 4, 256, 0, stream>>>(hb, s_h, al, ar, row_ptr, col, x1p, s1p);
    conv1_kernel<<<(N_NODES + 3) / 4, 256, 0, stream>>>(h, x1p, s1p, al, ar, row_ptr, col, zh);

    // fused epilogue GEMM (encoded + logits)
    zgemm_kernel<<<(N_NODES / 16), 256, 0, stream>>>(zh, W2, b2, W3, b3, out_encoded, out_logits);
}

// Round 14
// 346.346 us; speedup vs baseline: 1.2057x; 1.0215x over previous
//
#include <hip/hip_runtime.h>
#include <hip/hip_bf16.h>
#include <hip/hip_fp16.h>
#include <cmath>

#define N_NODES 50000
#define N_EDGES 800000
#define HID 64
#define HEADS 4
#define CONVS 2
#define CLS 16
#define SLOPE 0.2f
#define SCAN_B 1024
#define LOG2E 1.4426950408889634f

typedef unsigned int  uint32;
typedef unsigned short ushort16;

__device__ __forceinline__ ushort16 f2bf(float x) {
    union { float f; uint32 u; } v; v.f = x;
    uint32 r = v.u + 0x7fffu + ((v.u >> 16) & 1u);   // RNE
    return (ushort16)(r >> 16);
}
__device__ __forceinline__ float bf_lo(uint32 w) { return __uint_as_float(w << 16); }
__device__ __forceinline__ float bf_hi(uint32 w) { return __uint_as_float(w & 0xffff0000u); }

// ------ fused: per-type projections (LDS-staged feat tile) + edge histogram ------

template <int K>
__device__ __forceinline__ void proj_lds(const float* __restrict__ feat,
                                         const float* __restrict__ W,
                                         const float* __restrict__ b,
                                         float* __restrict__ h,
                                         ushort16* __restrict__ hb,
                                         float* __restrict__ s_out,
                                         int rows, int base_row, int blk,
                                         float* __restrict__ lds) {
    int tid  = threadIdx.x;
    int lane = tid & 63;
    int wid  = tid >> 6;
    int tile0 = blk * 32;                       // 32 rows per block
    int avail = rows - tile0; if (avail > 32) avail = 32;   // rows%8==0 -> avail%8==0

    const float4* g = reinterpret_cast<const float4*>(feat + (size_t)tile0 * K);
    float4* l4 = reinterpret_cast<float4*>(lds);
    int nv = avail * K / 4;
    for (int i = tid; i < nv; i += 256) l4[i] = g[i];
    __syncthreads();

    int r0 = wid * 8;                           // local row base for this wave
    if (r0 >= avail) return;

    float bb = b[lane];
    float acc[8];
    #pragma unroll
    for (int i = 0; i < 8; i++) acc[i] = bb;

    for (int kk = 0; kk < K; kk += 4) {
        float w0 = W[(kk + 0) * 64 + lane];
        float w1 = W[(kk + 1) * 64 + lane];
        float w2 = W[(kk + 2) * 64 + lane];
        float w3 = W[(kk + 3) * 64 + lane];
        #pragma unroll
        for (int i = 0; i < 8; i++) {
            float4 a4 = *reinterpret_cast<const float4*>(lds + (size_t)(r0 + i) * K + kk);
            acc[i] = fmaf(a4.x, w0, acc[i]);
            acc[i] = fmaf(a4.y, w1, acc[i]);
            acc[i] = fmaf(a4.z, w2, acc[i]);
            acc[i] = fmaf(a4.w, w3, acc[i]);
        }
    }

    #pragma unroll
    for (int i = 0; i < 8; i++) {
        int gr = base_row + tile0 + r0 + i;
        h[(size_t)gr * 64 + lane]  = acc[i];
        hb[(size_t)gr * 64 + lane] = f2bf(acc[i]);
    }
    #pragma unroll
    for (int i = 0; i < 8; i++) {
        float ssum = acc[i];
        #pragma unroll
        for (int off = 32; off; off >>= 1) ssum += __shfl_xor(ssum, off);
        if (lane == i) s_out[base_row + tile0 + r0 + i] = ssum;
    }
}

#define PB0 625           // 20000 / 32
#define PB1 469           // ceil(15000 / 32)
#define PB2 469
#define NPROJ (PB0 + PB1 + PB2)
#define PBH ((N_EDGES + 1023) / 1024)   // 4 edges/thread

__global__ __launch_bounds__(256)
void fused_proj_hist_kernel(const float* __restrict__ feat0, const float* __restrict__ W1_0, const float* __restrict__ b1_0,
                            const float* __restrict__ feat1, const float* __restrict__ W1_1, const float* __restrict__ b1_1,
                            const float* __restrict__ feat2, const float* __restrict__ W1_2, const float* __restrict__ b1_2,
                            float* __restrict__ h, ushort16* __restrict__ hb, float* __restrict__ s_out,
                            const int* __restrict__ dst, int* __restrict__ deg) {
    __shared__ float lds[32 * 256];   // 32 KB
    int bid = blockIdx.x;
    if (bid < PB0) {
        proj_lds<256>(feat0, W1_0, b1_0, h, hb, s_out, 20000, 0, bid, lds);
    } else if (bid < PB0 + PB1) {
        proj_lds<128>(feat1, W1_1, b1_1, h, hb, s_out, 15000, 20000, bid - PB0, lds);
    } else if (bid < NPROJ) {
        proj_lds<64>(feat2, W1_2, b1_2, h, hb, s_out, 15000, 35000, bid - (PB0 + PB1), lds);
    } else {
        int t4 = (bid - NPROJ) * 1024 + threadIdx.x * 4;
        if (t4 + 3 < N_EDGES) {
            int4 d4 = *reinterpret_cast<const int4*>(dst + t4);
            atomicAdd(&deg[d4.x], 1);
            atomicAdd(&deg[d4.y], 1);
            atomicAdd(&deg[d4.z], 1);
            atomicAdd(&deg[d4.w], 1);
        } else {
            for (int e = t4; e < N_EDGES; e++) atomicAdd(&deg[dst[e]], 1);
        }
    }
}

// ---------------- CSR scan ----------------

__global__ void scan1_kernel(const int* __restrict__ deg, int* __restrict__ row_ptr,
                             int* __restrict__ tops) {
    __shared__ int buf[SCAN_B];
    int i = blockIdx.x * SCAN_B + threadIdx.x;
    int v = (i < N_NODES) ? deg[i] : 0;
    buf[threadIdx.x] = v;
    __syncthreads();
    for (int off = 1; off < SCAN_B; off <<= 1) {
        int t = (threadIdx.x >= off) ? buf[threadIdx.x - off] : 0;
        __syncthreads();
        buf[threadIdx.x] += t;
        __syncthreads();
    }
    if (i < N_NODES) row_ptr[i + 1] = buf[threadIdx.x];
    if (threadIdx.x == SCAN_B - 1) tops[blockIdx.x] = buf[threadIdx.x];
}

__global__ void scan3_kernel(int* __restrict__ row_ptr, const int* __restrict__ tops) {
    __shared__ int pfx;
    if (threadIdx.x == 0) {
        int acc = 0;
        for (int b = 0; b < (int)blockIdx.x; b++) acc += tops[b];
        pfx = acc;
    }
    __syncthreads();
    int i = blockIdx.x * SCAN_B + threadIdx.x;
    if (i < N_NODES) row_ptr[i + 1] += pfx;
    if (i == 0 && blockIdx.x == 0) row_ptr[0] = 0;
}

__global__ void scatter_kernel(const int* __restrict__ src, const int* __restrict__ dst,
                               const int* __restrict__ row_ptr, int* __restrict__ cursor,
                               int* __restrict__ col) {
    int e = blockIdx.x * blockDim.x + threadIdx.x;
    if (e < 8) col[N_EDGES + e] = 0;   // pad (kept for safety)
    if (e < N_EDGES) {
        int d = dst[e];
        int pos = row_ptr[d] + atomicAdd(&cursor[d], 1);
        col[pos] = src[e];
    }
}

// ------- conv 0: wave-private LDS edge metadata (uniform ds_read), 4-deep x prefetch ----

__global__ __launch_bounds__(256)
void conv0_kernel(const ushort16* __restrict__ hb, const float* __restrict__ s_h,
                  const float* __restrict__ al, const float* __restrict__ ar,
                  const int* __restrict__ row_ptr, const int* __restrict__ col,
                  ushort16* __restrict__ x1p, float4* __restrict__ s1p) {
    __shared__ uint32 sh_off[4][72];
    __shared__ float  sh_s[4][72];
    int lane = threadIdx.x & 63;
    int wid  = threadIdx.x >> 6;
    int n = blockIdx.x * 4 + wid;
    if (n >= N_NODES) return;

    float sd = s_h[n];
    int base = row_ptr[n];
    int deg  = row_ptr[n + 1] - base;

    float alk[HEADS], ck[HEADS], alkB[HEADS], ckB[HEADS];
    float den[HEADS] = {0.f, 0.f, 0.f, 0.f}, num[HEADS] = {0.f, 0.f, 0.f, 0.f};
    #pragma unroll
    for (int hd = 0; hd < HEADS; hd++) {
        float a = al[(hd * CONVS + 0) * 64 + lane] * LOG2E;
        float c = ar[(hd * CONVS + 0) * 64 + lane] * LOG2E * sd;
        alk[hd] = a; ck[hd] = c; alkB[hd] = SLOPE * a; ckB[hd] = SLOPE * c;
    }

    uint32* offw = sh_off[wid];
    float*  ssw  = sh_s[wid];
    const char* xb = (const char*)hb + (size_t)lane * 2;   // 2B/lane, row = 128B

#define XL0(J)  ((uint32)*reinterpret_cast<const ushort16*>(xb + offw[J]))
#define C0C(J, XV)                                                                 \
    {                                                                              \
        float s_ = ssw[J];                                                         \
        float hf = __uint_as_float((XV) << 16);                                    \
        float w0 = exp2f(fmaxf(fmaf(alk[0], s_, ck[0]), fmaf(alkB[0], s_, ckB[0])));\
        float w1 = exp2f(fmaxf(fmaf(alk[1], s_, ck[1]), fmaf(alkB[1], s_, ckB[1])));\
        float w2 = exp2f(fmaxf(fmaf(alk[2], s_, ck[2]), fmaf(alkB[2], s_, ckB[2])));\
        float w3 = exp2f(fmaxf(fmaf(alk[3], s_, ck[3]), fmaf(alkB[3], s_, ckB[3])));\
        den[0] += w0; den[1] += w1; den[2] += w2; den[3] += w3;                    \
        num[0] = fmaf(hf, w0, num[0]); num[1] = fmaf(hf, w1, num[1]);              \
        num[2] = fmaf(hf, w2, num[2]); num[3] = fmaf(hf, w3, num[3]);              \
    }

    int done = 0;
    while (done < deg) {
        int CH = min(deg - done, 64);
        int c = col[base + done + ((lane < CH) ? lane : 0)];   // coalesced; dup lanes >= CH
        uint32 off = (uint32)c << 7;
        offw[lane] = off;
        ssw[lane]  = s_h[c];
        uint32 o0 = (uint32)__shfl((int)off, 0);
        if (lane < 4) offw[64 + lane] = o0;                    // pads for prefetch
        // wave-private LDS: within-wave lgkmcnt ordering, no barrier needed
        uint32 xA = XL0(0), xB = XL0(1), xC = XL0(2), xD = XL0(3);
        int ch4 = CH & ~3;
        for (int j = 0; j < ch4; j += 4) {
            C0C(j + 0, xA); xA = XL0(j + 4);
            C0C(j + 1, xB); xB = XL0(j + 5);
            C0C(j + 2, xC); xC = XL0(j + 6);
            C0C(j + 3, xD); xD = XL0(j + 7);
        }
        int rem = CH - ch4;
        if (rem > 0) C0C(ch4 + 0, xA);
        if (rem > 1) C0C(ch4 + 1, xB);
        if (rem > 2) C0C(ch4 + 2, xC);
        done += CH;
    }
#undef XL0
#undef C0C

    float o[HEADS];
    #pragma unroll
    for (int hd = 0; hd < HEADS; hd++) o[hd] = num[hd] / den[hd];

    uint32 lo = ((uint32)f2bf(o[0])) | (((uint32)f2bf(o[1])) << 16);
    uint32 hi = ((uint32)f2bf(o[2])) | (((uint32)f2bf(o[3])) << 16);
    *reinterpret_cast<uint2*>(x1p + ((size_t)n * 64 + lane) * 4) = make_uint2(lo, hi);

    float s0 = o[0], s1v = o[1], s2 = o[2], s3 = o[3];
    #pragma unroll
    for (int off = 32; off; off >>= 1) {
        s0 += __shfl_xor(s0, off); s1v += __shfl_xor(s1v, off);
        s2 += __shfl_xor(s2, off); s3  += __shfl_xor(s3, off);
    }
    if (lane == 0) s1p[n] = make_float4(s0, s1v, s2, s3);
}

// ------- conv 1: wave-private LDS edge metadata (uniform ds_read), 4-deep x prefetch ----

__global__ __launch_bounds__(256)
void conv1_kernel(const float* __restrict__ h, const ushort16* __restrict__ x1p,
                  const float4* __restrict__ s1p,
                  const float* __restrict__ al, const float* __restrict__ ar,
                  const int* __restrict__ row_ptr, const int* __restrict__ col,
                  uint2* __restrict__ zh /* [N][64 lanes][4 heads] fp16 */) {
    __shared__ uint32 sh_off[4][72];
    __shared__ float4 sh_s4[4][72];
    int lane = threadIdx.x & 63;
    int wid  = threadIdx.x >> 6;
    int n = blockIdx.x * 4 + wid;
    if (n >= N_NODES) return;

    int base = row_ptr[n];
    int deg  = row_ptr[n + 1] - base;

    float4 sdn = s1p[n];
    float sdv[HEADS] = {sdn.x, sdn.y, sdn.z, sdn.w};
    float alk[HEADS], ck[HEADS], alkB[HEADS], ckB[HEADS];
    float den[HEADS] = {0.f, 0.f, 0.f, 0.f}, num[HEADS] = {0.f, 0.f, 0.f, 0.f};
    #pragma unroll
    for (int hd = 0; hd < HEADS; hd++) {
        float a = al[(hd * CONVS + 1) * 64 + lane] * LOG2E;
        float c = ar[(hd * CONVS + 1) * 64 + lane] * LOG2E * sdv[hd];
        alk[hd] = a; ck[hd] = c; alkB[hd] = SLOPE * a; ckB[hd] = SLOPE * c;
    }

    uint32* offw = sh_off[wid];
    float4* s4w  = sh_s4[wid];
    const char* xb = (const char*)x1p + (size_t)lane * 8;   // 8B/lane, row = 512B

#define XL1(J)  (*reinterpret_cast<const uint2*>(xb + offw[J]))
#define C1C(J, XV)                                                                 \
    {                                                                              \
        float4 s = s4w[J];                                                         \
        float xf0 = bf_lo((XV).x), xf1 = bf_hi((XV).x);                            \
        float xf2 = bf_lo((XV).y), xf3 = bf_hi((XV).y);                            \
        float w0 = exp2f(fmaxf(fmaf(alk[0], s.x, ck[0]), fmaf(alkB[0], s.x, ckB[0])));\
        float w1 = exp2f(fmaxf(fmaf(alk[1], s.y, ck[1]), fmaf(alkB[1], s.y, ckB[1])));\
        float w2 = exp2f(fmaxf(fmaf(alk[2], s.z, ck[2]), fmaf(alkB[2], s.z, ckB[2])));\
        float w3 = exp2f(fmaxf(fmaf(alk[3], s.w, ck[3]), fmaf(alkB[3], s.w, ckB[3])));\
        den[0] += w0; den[1] += w1; den[2] += w2; den[3] += w3;                    \
        num[0] = fmaf(xf0, w0, num[0]); num[1] = fmaf(xf1, w1, num[1]);            \
        num[2] = fmaf(xf2, w2, num[2]); num[3] = fmaf(xf3, w3, num[3]);            \
    }

    int done = 0;
    while (done < deg) {
        int CH = min(deg - done, 64);
        int c = col[base + done + ((lane < CH) ? lane : 0)];   // coalesced; dup lanes >= CH
        uint32 off = (uint32)c << 9;
        offw[lane] = off;
        s4w[lane]  = s1p[c];
        uint32 o0 = (uint32)__shfl((int)off, 0);
        if (lane < 4) offw[64 + lane] = o0;                    // pads for prefetch
        uint2 xA = XL1(0), xB = XL1(1), xC = XL1(2), xD = XL1(3);
        int ch4 = CH & ~3;
        for (int j = 0; j < ch4; j += 4) {
            C1C(j + 0, xA); xA = XL1(j + 4);
            C1C(j + 1, xB); xB = XL1(j + 5);
            C1C(j + 2, xC); xC = XL1(j + 6);
            C1C(j + 3, xD); xD = XL1(j + 7);
        }
        int rem = CH - ch4;
        if (rem > 0) C1C(ch4 + 0, xA);
        if (rem > 1) C1C(ch4 + 1, xB);
        if (rem > 2) C1C(ch4 + 2, xC);
        done += CH;
    }
#undef XL1
#undef C1C

    float hres = h[(size_t)n * 64 + lane];
    float z0 = fmaxf(hres + num[0] / den[0], 0.f);
    float z1 = fmaxf(hres + num[1] / den[1], 0.f);
    float z2 = fmaxf(hres + num[2] / den[2], 0.f);
    float z3 = fmaxf(hres + num[3] / den[3], 0.f);

    __half2 p01 = __floats2half2_rn(z0, z1);
    __half2 p23 = __floats2half2_rn(z2, z3);
    uint2 pk;
    pk.x = *reinterpret_cast<uint32*>(&p01);
    pk.y = *reinterpret_cast<uint32*>(&p23);
    zh[(size_t)n * 64 + lane] = pk;   // coalesced 512B per wave
}

// ------- encoded = z @ W2 + b2, then logits = relu(enc) @ W3 + b3 (fused, 8 rows/wave) --

__global__ __launch_bounds__(256)
void zgemm_kernel(const uint2* __restrict__ zh, const float* __restrict__ W2,
                  const float* __restrict__ b2, const float* __restrict__ W3,
                  const float* __restrict__ b3,
                  float* __restrict__ out_encoded, float* __restrict__ out_logits) {
    int lane = threadIdx.x & 63;
    int wid  = threadIdx.x >> 6;
    int r0 = (blockIdx.x * 4 + wid) * 8;      // 8 rows per wave; N % 8 == 0
    if (r0 >= N_NODES) return;

    float bb = b2[lane];
    float acc[8];
    #pragma unroll
    for (int i = 0; i < 8; i++) acc[i] = bb;
    const uint2* z0 = zh + (size_t)r0 * 64;

    for (int q = 0; q < 64; q += 2) {
        const float* wp = W2 + q * 64 + lane;
        float w0 = wp[0];            // (hd0, q)
        float w1 = wp[4096];         // (hd1, q)
        float w2 = wp[8192];         // (hd2, q)
        float w3 = wp[12288];        // (hd3, q)
        float w4 = wp[64];           // (hd0, q+1)
        float w5 = wp[4160];         // (hd1, q+1)
        float w6 = wp[8256];         // (hd2, q+1)
        float w7 = wp[12352];        // (hd3, q+1)

        #pragma unroll
        for (int rr = 0; rr < 8; rr++) {
            uint4 zz = *reinterpret_cast<const uint4*>(z0 + rr * 64 + q);
            float2 fA = __half22float2(*reinterpret_cast<const __half2*>(&zz.x));
            float2 fB = __half22float2(*reinterpret_cast<const __half2*>(&zz.y));
            float2 fC = __half22float2(*reinterpret_cast<const __half2*>(&zz.z));
            float2 fD = __half22float2(*reinterpret_cast<const __half2*>(&zz.w));
            float a = acc[rr];
            a = fmaf(fA.x, w0, a);
            a = fmaf(fA.y, w1, a);
            a = fmaf(fB.x, w2, a);
            a = fmaf(fB.y, w3, a);
            a = fmaf(fC.x, w4, a);
            a = fmaf(fC.y, w5, a);
            a = fmaf(fD.x, w6, a);
            a = fmaf(fD.y, w7, a);
            acc[rr] = a;
        }
    }
    #pragma unroll
    for (int rr = 0; rr < 8; rr++)
        out_encoded[(size_t)(r0 + rr) * 64 + lane] = acc[rr];

    // fused logits: lane holds enc col; per row 16 shuffles + 2-step reduce
    int c16 = lane & 15;
    int k0  = (lane >> 4) * 16;
    #pragma unroll
    for (int rr = 0; rr < 8; rr++) {
        float er = fmaxf(acc[rr], 0.f);
        float part = 0.f;
        #pragma unroll
        for (int j = 0; j < 16; j++) {
            float ev = __shfl(er, k0 + j);
            part = fmaf(ev, W3[(k0 + j) * CLS + c16], part);
        }
        part += __shfl_xor(part, 16);
        part += __shfl_xor(part, 32);
        if (lane < CLS) out_logits[(size_t)(r0 + rr) * CLS + lane] = part + b3[lane];
    }
}

// ---------------- launch ----------------

extern "C" void kernel_launch(void* const* d_in, const int* in_sizes, int n_in,
                              void* d_out, int out_size, void* d_ws, size_t ws_size,
                              hipStream_t stream) {
    const float* feat0 = (const float*)d_in[0];
    const float* feat1 = (const float*)d_in[1];
    const float* feat2 = (const float*)d_in[2];
    const int*   src   = (const int*)d_in[3];
    const int*   dst   = (const int*)d_in[4];
    const float* W1_0  = (const float*)d_in[5];
    const float* b1_0  = (const float*)d_in[6];
    const float* W1_1  = (const float*)d_in[7];
    const float* b1_1  = (const float*)d_in[8];
    const float* W1_2  = (const float*)d_in[9];
    const float* b1_2  = (const float*)d_in[10];
    const float* al    = (const float*)d_in[11];
    const float* ar    = (const float*)d_in[12];
    const float* W2    = (const float*)d_in[13];
    const float* b2    = (const float*)d_in[14];
    const float* W3    = (const float*)d_in[15];
    const float* b3    = (const float*)d_in[16];

    float* out_logits  = (float*)d_out;
    float* out_encoded = (float*)d_out + (size_t)N_NODES * CLS;

    char* ws = (char*)d_ws;
    size_t off = 0;
    auto alloc = [&](size_t bytes) {
        void* p = ws + off;
        off = (off + bytes + 255) & ~(size_t)255;
        return p;
    };
    int*      row_ptr = (int*)alloc((N_NODES + 1) * sizeof(int));
    int*      degcur  = (int*)alloc(2 * N_NODES * sizeof(int));  // deg | cursor
    int*      tops    = (int*)alloc(64 * sizeof(int));
    int*      col     = (int*)alloc(((size_t)N_EDGES + 8) * sizeof(int));
    float*    h       = (float*)alloc((size_t)N_NODES * 64 * sizeof(float));
    ushort16* hb      = (ushort16*)alloc((size_t)N_NODES * 64 * sizeof(ushort16));
    float*    s_h     = (float*)alloc(N_NODES * sizeof(float));
    ushort16* x1p     = (ushort16*)alloc((size_t)N_NODES * 64 * 4 * sizeof(ushort16));
    float4*   s1p     = (float4*)alloc(N_NODES * sizeof(float4));
    uint2*    zh      = (uint2*)alloc((size_t)N_NODES * 64 * sizeof(uint2));
    int* deg    = degcur;
    int* cursor = degcur + N_NODES;
    (void)ws_size; (void)in_sizes; (void)n_in; (void)out_size;

    // zero deg + cursor in one shot
    (void)hipMemsetAsync(degcur, 0, 2 * N_NODES * sizeof(int), stream);

    // fused projections (LDS-staged, 8 rows/wave) + histogram (4 edges/thread)
    fused_proj_hist_kernel<<<NPROJ + PBH, 256, 0, stream>>>(
        feat0, W1_0, b1_0, feat1, W1_1, b1_1, feat2, W1_2, b1_2,
        h, hb, s_h, dst, deg);

    int nb = (N_NODES + SCAN_B - 1) / SCAN_B;
    scan1_kernel<<<nb, SCAN_B, 0, stream>>>(deg, row_ptr, tops);
    scan3_kernel<<<nb, SCAN_B, 0, stream>>>(row_ptr, tops);
    scatter_kernel<<<(N_EDGES + 255) / 256, 256, 0, stream>>>(src, dst, row_ptr, cursor, col);

    // convs (1 wave per node)
    conv0_kernel<<<(N_NODES + 3) / 4, 256, 0, stream>>>(hb, s_h, al, ar, row_ptr, col, x1p, s1p);
    conv1_kernel<<<(N_NODES + 3) / 4, 256, 0, stream>>>(h, x1p, s1p, al, ar, row_ptr, col, zh);

    // fused epilogue GEMM (encoded + logits), 8 rows/wave
    zgemm_kernel<<<(N_NODES + 31) / 32, 256, 0, stream>>>(zh, W2, b2, W3, b3, out_encoded, out_logits);
}